// Round 5
// baseline (182.623 us; speedup 1.0000x reference)
//
#include <hip/hip_runtime.h>
#include <hip/hip_bf16.h>

#define B_ 8
#define L_ 4096
#define C_ 256
#define H_ 8
#define D_ 32
#define CHUNK_ 128
#define NC_ 32
#define M_ (B_*L_)   // 32768

typedef _Float16 f16x8 __attribute__((ext_vector_type(8)));
typedef _Float16 f16x4 __attribute__((ext_vector_type(4)));
typedef float    f32x4 __attribute__((ext_vector_type(4)));

#define GLOAD_LDS16(g, l) __builtin_amdgcn_global_load_lds( \
    (const __attribute__((address_space(1))) unsigned int*)(g), \
    (__attribute__((address_space(3))) unsigned int*)(l), 16, 0, 0)

// ---------------------------------------------------------------------------
// qkv GEMM with fused input prep: A-tile staged from f32 x+rel (add+cvt in
// registers -> ds_write_b128), B-tile staged from f32 qkv_w (cvt). Replaces
// the k_prep kernel entirely (numerically identical: f32 add then f16 round).
// XCD-swizzled 1D grid (1536 blocks). Epilogue (RMS-norm / V-transpose)
// unchanged from the verified kernel.
// ---------------------------------------------------------------------------
__global__ __launch_bounds__(256) void k_qkv_gemm(
    const float* __restrict__ x, const float* __restrict__ rel,
    const float* __restrict__ qw,
    const float* __restrict__ qg, const float* __restrict__ kg,
    _Float16* __restrict__ Qg, _Float16* __restrict__ Kg, _Float16* __restrict__ Vtg)
{
    __shared__ __align__(16) char smem[34816];      // max(As+Bs=16K, Ws)
    _Float16* As = (_Float16*)smem;                 // [128][32]
    _Float16* Bs = As + 128 * 32;                   // [128][32]
    _Float16* Ws = (_Float16*)smem;                 // epilogue staging

    const int blk = blockIdx.x;
    const int xcd = blk & 7;
    const int t   = blk >> 3;                       // 0..191
    const int by  = xcd * 32 + (t & 31);
    const int bx  = t >> 5;                         // 0..5
    const int m0 = by * 128;
    const int n0 = bx * 128;

    const int tid = threadIdx.x;
    const int wv = tid >> 6, ln = tid & 63;
    const int wm = (wv >> 1) * 64, wn = (wv & 1) * 64;
    const int fr = ln & 15, fk = (ln >> 4) * 8;

    // staging lane mapping: row sr (0..15) within the wave's 16-row group,
    // col sc (0,8,16,24); two halves (rows +0 / +64)
    const int sr = ln >> 2, sc = (ln & 3) * 8;
    const size_t ar0 = (size_t)(m0 + wv * 16 + sr);
    const size_t ar1 = ar0 + 64;
    const float* xp0 = x   + ar0 * 256 + sc;
    const float* xp1 = x   + ar1 * 256 + sc;
    const float* rp0 = rel + (size_t)(ar0 & 4095) * 256 + sc;
    const float* rp1 = rel + (size_t)(ar1 & 4095) * 256 + sc;
    const float* wp0 = qw  + (size_t)(n0 + wv * 16 + sr) * 256 + sc;
    const float* wp1 = qw  + (size_t)(n0 + 64 + wv * 16 + sr) * 256 + sc;
    _Float16* as0 = As + (wv * 16 + sr) * 32 + sc;
    _Float16* as1 = As + (64 + wv * 16 + sr) * 32 + sc;
    _Float16* bs0 = Bs + (wv * 16 + sr) * 32 + sc;
    _Float16* bs1 = Bs + (64 + wv * 16 + sr) * 32 + sc;

    f32x4 acc[4][4] = {};

#pragma unroll
    for (int k0 = 0; k0 < 256; k0 += 32) {
        {   // A half 0: h = f16(x + rel)
            float4 a0 = *(const float4*)(xp0 + k0);
            float4 a1 = *(const float4*)(xp0 + k0 + 4);
            float4 b0 = *(const float4*)(rp0 + k0);
            float4 b1 = *(const float4*)(rp0 + k0 + 4);
            f16x8 o = { (_Float16)(a0.x + b0.x), (_Float16)(a0.y + b0.y),
                        (_Float16)(a0.z + b0.z), (_Float16)(a0.w + b0.w),
                        (_Float16)(a1.x + b1.x), (_Float16)(a1.y + b1.y),
                        (_Float16)(a1.z + b1.z), (_Float16)(a1.w + b1.w) };
            *(f16x8*)as0 = o;
        }
        {   // A half 1
            float4 a0 = *(const float4*)(xp1 + k0);
            float4 a1 = *(const float4*)(xp1 + k0 + 4);
            float4 b0 = *(const float4*)(rp1 + k0);
            float4 b1 = *(const float4*)(rp1 + k0 + 4);
            f16x8 o = { (_Float16)(a0.x + b0.x), (_Float16)(a0.y + b0.y),
                        (_Float16)(a0.z + b0.z), (_Float16)(a0.w + b0.w),
                        (_Float16)(a1.x + b1.x), (_Float16)(a1.y + b1.y),
                        (_Float16)(a1.z + b1.z), (_Float16)(a1.w + b1.w) };
            *(f16x8*)as1 = o;
        }
        {   // B half 0: f16(qkv_w)
            float4 a0 = *(const float4*)(wp0 + k0);
            float4 a1 = *(const float4*)(wp0 + k0 + 4);
            f16x8 o = { (_Float16)a0.x, (_Float16)a0.y, (_Float16)a0.z, (_Float16)a0.w,
                        (_Float16)a1.x, (_Float16)a1.y, (_Float16)a1.z, (_Float16)a1.w };
            *(f16x8*)bs0 = o;
        }
        {   // B half 1
            float4 a0 = *(const float4*)(wp1 + k0);
            float4 a1 = *(const float4*)(wp1 + k0 + 4);
            f16x8 o = { (_Float16)a0.x, (_Float16)a0.y, (_Float16)a0.z, (_Float16)a0.w,
                        (_Float16)a1.x, (_Float16)a1.y, (_Float16)a1.z, (_Float16)a1.w };
            *(f16x8*)bs1 = o;
        }
        __syncthreads();
        f16x8 af[4], bf[4];
#pragma unroll
        for (int i = 0; i < 4; ++i)
            af[i] = *(const f16x8*)(As + (wm + i * 16 + fr) * 32 + fk);
#pragma unroll
        for (int j = 0; j < 4; ++j)
            bf[j] = *(const f16x8*)(Bs + (wn + j * 16 + fr) * 32 + fk);
#pragma unroll
        for (int i = 0; i < 4; ++i)
#pragma unroll
            for (int j = 0; j < 4; ++j)
                acc[i][j] = __builtin_amdgcn_mfma_f32_16x16x32_f16(
                    af[i], bf[j], acc[i][j], 0, 0, 0);
        __syncthreads();
    }

    const int cr = (ln >> 4) * 4, cc = ln & 15;
    const int kind = n0 >> 8;                 // 0=Q 1=K 2=V
    const int col0 = (n0 & 255) + wn;
    const int bb = m0 >> 12, l00 = m0 & 4095;
    const int hbase = (n0 & 255) >> 5;

    if (kind < 2) {
        // fused RMS-norm (q's D^-1/2 pre-scale cancels; scale-invariant)
        const float* gsrc = kind ? kg : qg;
        float gma[2][2];
#pragma unroll
        for (int jp = 0; jp < 2; ++jp)
#pragma unroll
            for (int jj = 0; jj < 2; ++jj)
                gma[jp][jj] = gsrc[((col0 >> 5) + jp) * 32 + jj * 16 + cc];
#pragma unroll
        for (int i = 0; i < 4; ++i)
#pragma unroll
            for (int r = 0; r < 4; ++r) {
                const int irow = wm + i * 16 + cr + r;
#pragma unroll
                for (int jp = 0; jp < 2; ++jp) {
                    const float a0 = acc[i][jp * 2][r];
                    const float a1 = acc[i][jp * 2 + 1][r];
                    float ss = a0 * a0 + a1 * a1;
                    ss += __shfl_xor(ss, 1);
                    ss += __shfl_xor(ss, 2);
                    ss += __shfl_xor(ss, 4);
                    ss += __shfl_xor(ss, 8);
                    const float sc2 = 5.656854249492381f / fmaxf(sqrtf(ss), 1e-12f);
                    Ws[irow * 136 + wn + jp * 32 + cc]      = (_Float16)(a0 * sc2 * gma[jp][0]);
                    Ws[irow * 136 + wn + jp * 32 + 16 + cc] = (_Float16)(a1 * sc2 * gma[jp][1]);
                }
            }
        __syncthreads();
        _Float16* P = kind ? Kg : Qg;
#pragma unroll
        for (int kk = 0; kk < 8; ++kk) {
            const int c = kk * 256 + tid;             // 0..2047 f16x8 chunks
            const int hh = c >> 9;
            const int rr = (c >> 2) & 127;
            const int part = (c & 3) * 8;
            f16x8 v8 = *(const f16x8*)(Ws + rr * 136 + hh * 32 + part);
            *(f16x8*)(P + ((size_t)(bb * 8 + hbase + hh) * 4096 + l00 + rr) * 32 + part) = v8;
        }
    } else {
        // V: transpose through LDS (stride 132: 2-way banks) -> [bh][e][4096]
#pragma unroll
        for (int i = 0; i < 4; ++i)
#pragma unroll
            for (int j = 0; j < 4; ++j) {
                const int colL = wn + j * 16 + cc;    // 0..127
                const int row0 = wm + i * 16 + cr;    // 4-aligned
                f16x4 v4 = { (_Float16)acc[i][j][0], (_Float16)acc[i][j][1],
                             (_Float16)acc[i][j][2], (_Float16)acc[i][j][3] };
                *(f16x4*)(Ws + colL * 132 + row0) = v4;
            }
        __syncthreads();
#pragma unroll
        for (int kk = 0; kk < 8; ++kk) {
            const int q = kk * 256 + tid;             // 0..2047
            const int c = q >> 4;                     // col 0..127
            const int seg = q & 15;                   // 8-row segment
            const int col = (n0 & 255) + c;
            const int hh = col >> 5, e = col & 31;
            f16x8 v8 = *(const f16x8*)(Ws + c * 132 + seg * 8);
            *(f16x8*)(Vtg + ((size_t)(bb * 8 + hh) * 32 + e) * 4096 + l00 + seg * 8) = v8;
        }
    }
}

// ---------------------------------------------------------------------------
// Per-chunk KV outer product via MFMA: one wave per chunk (verified r0 form).
// KV^T[e][d] = sum_pos V[pos][e] * K[pos][d] * exp(-s*(128-pos)).
// ---------------------------------------------------------------------------
__global__ __launch_bounds__(64) void k_chunk_kv(
    const _Float16* __restrict__ Kg, const _Float16* __restrict__ Vtg,
    float* __restrict__ kvbuf)
{
    __shared__ _Float16 Vp[32 * 136];   // [e][pos]
    __shared__ _Float16 Kp[32 * 136];   // [d][pos]
    const int blk = blockIdx.x;
    const int n  = blk & 31;
    const int bh = blk >> 5;
    const int h  = bh & 7;
    const float sl2 = exp2f(-(float)(h + 1)) * 1.44269504f;
    const int ln = threadIdx.x;
    const _Float16* Kc = Kg  + ((size_t)bh * 4096 + n * CHUNK_) * 32;
    const _Float16* Vc = Vtg + (size_t)bh * 32 * 4096 + n * CHUNK_;
#pragma unroll
    for (int i = 0; i < 8; ++i) {
        const int flat = i * 64 + ln;          // 0..511
        const int e = flat >> 4, seg = flat & 15;
        f16x8 v8 = *(const f16x8*)(Vc + (size_t)e * 4096 + seg * 8);
        *(f16x8*)(Vp + e * 136 + seg * 8) = v8;
        const int pos = flat >> 2, d0 = (flat & 3) * 8;
        f16x8 k8 = *(const f16x8*)(Kc + flat * 8);
#pragma unroll
        for (int j = 0; j < 8; ++j) Kp[(d0 + j) * 136 + pos] = k8[j];
    }
    __syncthreads();
    const int fr = ln & 15, fk = (ln >> 4) * 8;
    const float r = exp2f(sl2);
    float rj[8];
    rj[0] = 1.f;
#pragma unroll
    for (int j = 1; j < 8; ++j) rj[j] = rj[j - 1] * r;
    f32x4 acc[2][2] = {};
    for (int k0 = 0; k0 < 128; k0 += 32) {
        const float e0 = exp2f(-sl2 * (float)(CHUNK_ - (k0 + fk)));
        f16x8 av[2], bd[2];
#pragma unroll
        for (int i = 0; i < 2; ++i)
            av[i] = *(const f16x8*)(Vp + (i * 16 + fr) * 136 + k0 + fk);
#pragma unroll
        for (int jt = 0; jt < 2; ++jt) {
            f16x8 kraw = *(const f16x8*)(Kp + (jt * 16 + fr) * 136 + k0 + fk);
            f16x8 kb;
#pragma unroll
            for (int j = 0; j < 8; ++j)
                kb[j] = (_Float16)((float)kraw[j] * (e0 * rj[j]));
            bd[jt] = kb;
        }
#pragma unroll
        for (int i = 0; i < 2; ++i)
#pragma unroll
            for (int jt = 0; jt < 2; ++jt)
                acc[i][jt] = __builtin_amdgcn_mfma_f32_16x16x32_f16(
                    av[i], bd[jt], acc[i][jt], 0, 0, 0);
    }
    const int cr = (ln >> 4) * 4, cc = ln & 15;
    float* outp = kvbuf + (size_t)blk * 1024;
#pragma unroll
    for (int i = 0; i < 2; ++i)
#pragma unroll
        for (int jt = 0; jt < 2; ++jt)
#pragma unroll
            for (int rr = 0; rr < 4; ++rr)
                outp[(i * 16 + cr + rr) * 32 + jt * 16 + cc] = acc[i][jt][rr];
}

// ---------------------------------------------------------------------------
// Chunk-state scan: 256 single-wave blocks (bh x quarter-state), verified r2.
// ---------------------------------------------------------------------------
__global__ __launch_bounds__(64) void k_scan(float* __restrict__ kvbuf)
{
    const int blk = blockIdx.x;            // 256 = 64 bh * 4 groups
    const int bh  = blk >> 2;
    const int grp = blk & 3;
    const int tid = threadIdx.x;           // 64
    const float slope = exp2f(-(float)((bh & 7) + 1));
    const float bd = __expf(-slope * (float)CHUNK_);
    float4 st = {0.f, 0.f, 0.f, 0.f};
    float4* base = (float4*)(kvbuf + (size_t)bh * NC_ * 1024) + grp * 64 + tid;
#pragma unroll
    for (int g = 0; g < 4; ++g) {
        float4 tmp[8];
#pragma unroll
        for (int k = 0; k < 8; ++k) tmp[k] = base[(g * 8 + k) * 256];
#pragma unroll
        for (int k = 0; k < 8; ++k) {
            base[(g * 8 + k) * 256] = st;
            st.x = bd * st.x + tmp[k].x;
            st.y = bd * st.y + tmp[k].y;
            st.z = bd * st.z + tmp[k].z;
            st.w = bd * st.w + tmp[k].w;
        }
    }
}

// ---------------------------------------------------------------------------
// MFMA attention, barrier-free + load-balanced triangle (verified r2 form).
// ---------------------------------------------------------------------------
__global__ __launch_bounds__(256) void k_attn(
    const _Float16* __restrict__ Qg, const _Float16* __restrict__ Kg,
    const _Float16* __restrict__ Vtg, const float* __restrict__ kvbuf,
    _Float16* __restrict__ attnp)
{
    __shared__ __align__(16) _Float16 Ss[128 * 144];   // S~ ; Os alias (own rows)
    const int blk = blockIdx.x;
    const int n  = blk & 31;
    const int bh = blk >> 5;
    const int h  = bh & 7;
    const float sl2 = exp2f(-(float)(h + 1)) * 1.44269504f;
    const int tid = threadIdx.x;
    const int wv = tid >> 6, ln = tid & 63;
    const int fr = ln & 15, fk = (ln >> 4) * 8;
    const int cr = (ln >> 4) * 4, cc = ln & 15;
    const int rb0 = wv;          // owned row-blocks (16 rows each)
    const int rb1 = 7 - wv;

    const _Float16* Qc = Qg + ((size_t)bh * 4096 + n * CHUNK_) * 32;
    const _Float16* Kc = Kg + ((size_t)bh * 4096 + n * CHUNK_) * 32;
    const _Float16* Vc = Vtg + (size_t)bh * 32 * 4096 + n * CHUNK_;
    const float* kvp = kvbuf + (size_t)blk * 1024;     // KV^T [e][d] f32

    // Q fragments for the two owned row-blocks
    f16x8 aq0 = *(const f16x8*)(Qc + (rb0 * 16 + fr) * 32 + fk);
    f16x8 aq1 = *(const f16x8*)(Qc + (rb1 * 16 + fr) * 32 + fk);

    // inter-chunk: KV state global->reg->f16, 4 MFMAs
    f32x4 iacc[2][2] = {};
#pragma unroll
    for (int ct = 0; ct < 2; ++ct) {
        const float* kp = kvp + (ct * 16 + fr) * 32 + fk;
        f32x4 k0 = *(const f32x4*)kp;
        f32x4 k1 = *(const f32x4*)(kp + 4);
        f16x8 bkv = { (_Float16)k0[0], (_Float16)k0[1], (_Float16)k0[2], (_Float16)k0[3],
                      (_Float16)k1[0], (_Float16)k1[1], (_Float16)k1[2], (_Float16)k1[3] };
        iacc[0][ct] = __builtin_amdgcn_mfma_f32_16x16x32_f16(aq0, bkv, iacc[0][ct], 0, 0, 0);
        iacc[1][ct] = __builtin_amdgcn_mfma_f32_16x16x32_f16(aq1, bkv, iacc[1][ct], 0, 0, 0);
    }

    // decay factors: er(row)=exp2(-sl2*row) (reused as q_decay), ej(col)=exp2(sl2*col)
    const float c1  = exp2f(-sl2);
    const float r16 = exp2f(sl2 * 16.f);
    float er0[4], er1[4];
    {
        float e0 = exp2f(-sl2 * (float)(rb0 * 16 + cr));
        float e1 = exp2f(-sl2 * (float)(rb1 * 16 + cr));
#pragma unroll
        for (int r = 0; r < 4; ++r) { er0[r] = e0; er1[r] = e1; e0 *= c1; e1 *= c1; }
    }

    // S phase: 9 MFMAs/wave, masked + stored immediately (short sacc life)
    float ej = exp2f(sl2 * (float)cc);
#pragma unroll
    for (int j = 0; j < 8; ++j) {
        if (j <= rb1) {                                // wave-uniform
            f16x8 bk = *(const f16x8*)(Kc + (j * 16 + fr) * 32 + fk);
            f32x4 z = {};
            f32x4 s1 = __builtin_amdgcn_mfma_f32_16x16x32_f16(aq1, bk, z, 0, 0, 0);
            f32x4 s0 = {};
            if (j <= rb0)
                s0 = __builtin_amdgcn_mfma_f32_16x16x32_f16(aq0, bk, z, 0, 0, 0);
            const int jcol = j * 16 + cc;
#pragma unroll
            for (int r = 0; r < 4; ++r) {
                const int i1 = rb1 * 16 + cr + r;
                const float w1 = (jcol <= i1) ? ej * er1[r] : 0.f;
                Ss[i1 * 144 + jcol] = (_Float16)(s1[r] * w1);
                if (j <= rb0) {
                    const int i0 = rb0 * 16 + cr + r;
                    const float w0 = (jcol <= i0) ? ej * er0[r] : 0.f;
                    Ss[i0 * 144 + jcol] = (_Float16)(s0[r] * w0);
                }
            }
        }
        ej *= r16;
    }

    // the even row-block's last PV k-block reads 16 cols past the triangle:
    // zero-pad that strip (exactly one even rb per wave)
    {
        const int rbe = (wv & 1) ? rb1 : rb0;
#pragma unroll
        for (int r = 0; r < 4; ++r)
            Ss[(rbe * 16 + cr + r) * 144 + (rbe + 1) * 16 + cc] = (_Float16)0;
    }

    // PV: 5 k-block-halves/wave; own-row LDS reads, V frags from global (L2)
    const int km0 = (rb0 >> 1) + 1;
    const int km1 = (rb1 >> 1) + 1;                    // km1 >= km0
    f32x4 oacc[2][2] = {};
#pragma unroll
    for (int k = 0; k < 4; ++k) {
        if (k < km1) {                                 // wave-uniform
            f16x8 bv0 = *(const f16x8*)(Vc + (size_t)(fr) * 4096 + k * 32 + fk);
            f16x8 bv1 = *(const f16x8*)(Vc + (size_t)(16 + fr) * 4096 + k * 32 + fk);
            f16x8 as1 = *(const f16x8*)(Ss + (rb1 * 16 + fr) * 144 + k * 32 + fk);
            oacc[1][0] = __builtin_amdgcn_mfma_f32_16x16x32_f16(as1, bv0, oacc[1][0], 0, 0, 0);
            oacc[1][1] = __builtin_amdgcn_mfma_f32_16x16x32_f16(as1, bv1, oacc[1][1], 0, 0, 0);
            if (k < km0) {
                f16x8 as0 = *(const f16x8*)(Ss + (rb0 * 16 + fr) * 144 + k * 32 + fk);
                oacc[0][0] = __builtin_amdgcn_mfma_f32_16x16x32_f16(as0, bv0, oacc[0][0], 0, 0, 0);
                oacc[0][1] = __builtin_amdgcn_mfma_f32_16x16x32_f16(as0, bv1, oacc[0][1], 0, 0, 0);
            }
        }
    }

    // epilogue: combine intra+inter into Os (alias of own Ss rows), then store
#pragma unroll
    for (int r = 0; r < 4; ++r) {
        const int i0 = rb0 * 16 + cr + r;
        const int i1 = rb1 * 16 + cr + r;
        Ss[i0 * 144 + cc]      = (_Float16)(oacc[0][0][r] + er0[r] * iacc[0][0][r]);
        Ss[i0 * 144 + 16 + cc] = (_Float16)(oacc[0][1][r] + er0[r] * iacc[0][1][r]);
        Ss[i1 * 144 + cc]      = (_Float16)(oacc[1][0][r] + er1[r] * iacc[1][0][r]);
        Ss[i1 * 144 + 16 + cc] = (_Float16)(oacc[1][1][r] + er1[r] * iacc[1][1][r]);
    }
    _Float16* abase = attnp + ((size_t)bh * 4096 + n * CHUNK_) * 32;
    {
        const int rloc = ln >> 2, part = (ln & 3) * 8;
        const int i0 = rb0 * 16 + rloc;
        const int i1 = rb1 * 16 + rloc;
        f16x8 v0 = *(const f16x8*)(Ss + i0 * 144 + part);
        f16x8 v1 = *(const f16x8*)(Ss + i1 * 144 + part);
        *(f16x8*)(abase + i0 * 32 + part) = v0;
        *(f16x8*)(abase + i1 * 32 + part) = v1;
    }
}

// ---------------------------------------------------------------------------
// proj GEMM: out = attn @ proj_w^T + b. A from packed [bh][l][32] via
// global_load_lds (f16); B reg-staged from f32 proj_w (cvt in staging --
// replaces prep's weight conversion). XCD-swizzled 1D grid (512 blocks).
// ---------------------------------------------------------------------------
__global__ __launch_bounds__(256) void k_proj_gemm(
    const _Float16* __restrict__ attnp, const float* __restrict__ pw,
    const float* __restrict__ bias, float* __restrict__ Cc)
{
    __shared__ _Float16 As[128 * 32];
    __shared__ _Float16 Bs[128 * 32];
    const int blk = blockIdx.x;
    const int xcd = blk & 7;
    const int t   = blk >> 3;                       // 0..63
    const int m0 = (xcd * 32 + (t & 31)) * 128;
    const int n0 = (t >> 5) * 128;

    const int tid = threadIdx.x;
    const int wv = tid >> 6, ln = tid & 63;
    const int lr = ln >> 2;
    const int lc = (ln & 3) * 8;
    const int wm = (wv >> 1) * 64;
    const int wn = (wv & 1) * 64;
    const int fr = ln & 15;
    const int fk = (ln >> 4) * 8;

    f32x4 acc[4][4] = {};
    const int gmrow = m0 + wv * 16 + lr;
    const _Float16* ga = attnp +
        ((size_t)(gmrow >> 12) * 8 * 4096 + (gmrow & 4095)) * 32 + lc;

    // B staging pointers (f32 weights)
    const int sr = lr, sc = lc;
    const float* wp0 = pw + (size_t)(n0 + wv * 16 + sr) * 256 + sc;
    const float* wp1 = pw + (size_t)(n0 + 64 + wv * 16 + sr) * 256 + sc;
    _Float16* bs0 = Bs + (wv * 16 + sr) * 32 + sc;
    _Float16* bs1 = Bs + (64 + wv * 16 + sr) * 32 + sc;

#pragma unroll
    for (int k0 = 0; k0 < 256; k0 += 32) {
        const size_t hoff = (size_t)(k0 >> 5) * (4096 * 32);
        GLOAD_LDS16(ga + hoff,           As + (wv * 16) * 32);
        GLOAD_LDS16(ga + hoff + 64 * 32, As + (64 + wv * 16) * 32);
        {
            float4 a0 = *(const float4*)(wp0 + k0);
            float4 a1 = *(const float4*)(wp0 + k0 + 4);
            f16x8 o = { (_Float16)a0.x, (_Float16)a0.y, (_Float16)a0.z, (_Float16)a0.w,
                        (_Float16)a1.x, (_Float16)a1.y, (_Float16)a1.z, (_Float16)a1.w };
            *(f16x8*)bs0 = o;
        }
        {
            float4 a0 = *(const float4*)(wp1 + k0);
            float4 a1 = *(const float4*)(wp1 + k0 + 4);
            f16x8 o = { (_Float16)a0.x, (_Float16)a0.y, (_Float16)a0.z, (_Float16)a0.w,
                        (_Float16)a1.x, (_Float16)a1.y, (_Float16)a1.z, (_Float16)a1.w };
            *(f16x8*)bs1 = o;
        }
        __syncthreads();
        f16x8 af[4], bf[4];
#pragma unroll
        for (int i = 0; i < 4; ++i)
            af[i] = *(const f16x8*)(As + (wm + i * 16 + fr) * 32 + fk);
#pragma unroll
        for (int j = 0; j < 4; ++j)
            bf[j] = *(const f16x8*)(Bs + (wn + j * 16 + fr) * 32 + fk);
#pragma unroll
        for (int i = 0; i < 4; ++i)
#pragma unroll
            for (int j = 0; j < 4; ++j)
                acc[i][j] = __builtin_amdgcn_mfma_f32_16x16x32_f16(
                    af[i], bf[j], acc[i][j], 0, 0, 0);
        __syncthreads();
    }
    const int cr = (ln >> 4) * 4;
    const int cc = ln & 15;
#pragma unroll
    for (int i = 0; i < 4; ++i)
#pragma unroll
        for (int j = 0; j < 4; ++j) {
            const int row = m0 + wm + i * 16 + cr;
            const int col = n0 + wn + j * 16 + cc;
            float* cp = Cc + (size_t)row * 256 + col;
            const float bb = bias[col];
#pragma unroll
            for (int r = 0; r < 4; ++r) cp[(size_t)r * 256] = acc[i][j][r] + bb;
        }
}

// ---------------------------------------------------------------------------
extern "C" void kernel_launch(void* const* d_in, const int* in_sizes, int n_in,
                              void* d_out, int out_size, void* d_ws, size_t ws_size,
                              hipStream_t stream)
{
    const float* x     = (const float*)d_in[0];
    const float* rel   = (const float*)d_in[1];
    const float* qkv_w = (const float*)d_in[2];
    const float* qg    = (const float*)d_in[3];
    const float* kg    = (const float*)d_in[4];
    const float* pw    = (const float*)d_in[5];
    const float* pb    = (const float*)d_in[6];
    float* out = (float*)d_out;
    char* wsb = (char*)d_ws;

    float*    kvb   = (float*)wsb;                            // 8 MB
    _Float16* Qg    = (_Float16*)(wsb + ((size_t)8  << 20));  // 16 MB
    _Float16* Kg    = (_Float16*)(wsb + ((size_t)24 << 20));  // 16 MB
    _Float16* Vtg   = (_Float16*)(wsb + ((size_t)40 << 20));  // 16 MB
    _Float16* attnp = (_Float16*)(wsb + ((size_t)56 << 20));  // 16 MB

    k_qkv_gemm<<<1536, 256, 0, stream>>>(x, rel, qkv_w, qg, kg, Qg, Kg, Vtg);
    k_chunk_kv<<<2048, 64, 0, stream>>>(Kg, Vtg, kvb);
    k_scan<<<256, 64, 0, stream>>>(kvb);
    k_attn<<<2048, 256, 0, stream>>>(Qg, Kg, Vtg, kvb, attnp);
    k_proj_gemm<<<512, 256, 0, stream>>>(attnp, pw, pb, out);
}

// Round 6
// 171.920 us; speedup vs baseline: 1.0623x; 1.0623x over previous
//
#include <hip/hip_runtime.h>
#include <hip/hip_bf16.h>

#define B_ 8
#define L_ 4096
#define C_ 256
#define H_ 8
#define D_ 32
#define CHUNK_ 128
#define NC_ 32
#define M_ (B_*L_)   // 32768

typedef _Float16 f16x8 __attribute__((ext_vector_type(8)));
typedef _Float16 f16x4 __attribute__((ext_vector_type(4)));
typedef float    f32x4 __attribute__((ext_vector_type(4)));

#define GLOAD_LDS16(g, l) __builtin_amdgcn_global_load_lds( \
    (const __attribute__((address_space(1))) unsigned int*)(g), \
    (__attribute__((address_space(3))) unsigned int*)(l), 16, 0, 0)

// ---------------------------------------------------------------------------
// Prep: h = f16(x + rel_pos)  and  weights -> f16   (verified r0 form)
// ---------------------------------------------------------------------------
__global__ __launch_bounds__(256) void k_prep(
    const float* __restrict__ x, const float* __restrict__ rel,
    const float* __restrict__ qw, const float* __restrict__ pw,
    _Float16* __restrict__ h, _Float16* __restrict__ qwb, _Float16* __restrict__ pwb)
{
    const int bx = blockIdx.x;
    if (bx < 4096) {
        const int i = (bx * 256 + threadIdx.x) * 8;
        float4 x0 = *(const float4*)(x + i);
        float4 x1 = *(const float4*)(x + i + 4);
        const int ri = i & (L_ * C_ - 1);
        float4 r0 = *(const float4*)(rel + ri);
        float4 r1 = *(const float4*)(rel + ri + 4);
        f16x8 o = { (_Float16)(x0.x + r0.x), (_Float16)(x0.y + r0.y),
                    (_Float16)(x0.z + r0.z), (_Float16)(x0.w + r0.w),
                    (_Float16)(x1.x + r1.x), (_Float16)(x1.y + r1.y),
                    (_Float16)(x1.z + r1.z), (_Float16)(x1.w + r1.w) };
        *(f16x8*)(h + i) = o;
    } else {
        const int i = ((bx - 4096) * 256 + threadIdx.x) * 4;
        const float* src; _Float16* dst; int off;
        if (i < 768 * 256) { src = qw; dst = qwb; off = i; }
        else               { src = pw; dst = pwb; off = i - 768 * 256; }
        float4 v = *(const float4*)(src + off);
        f16x4 o = { (_Float16)v.x, (_Float16)v.y, (_Float16)v.z, (_Float16)v.w };
        *(f16x4*)(dst + off) = o;
    }
}

// ---------------------------------------------------------------------------
// qkv GEMM, 2-PHASE double-buffered schedule (T3-minimum): stage tile t+1
// via global_load_lds BEFORE computing tile t; ONE __syncthreads per K-step
// (its vmcnt(0) drain covers the staged loads; barrier also fences buffer
// reuse). 9 barriers vs 16; global latency hides under ds_read+MFMA.
// LDS: dbuf 2x16KB unions with 34.8KB epilogue staging -> occupancy
// unchanged. Staging addrs / fragments / MFMA / epilogue verbatim r2.
// ---------------------------------------------------------------------------
__global__ __launch_bounds__(256) void k_qkv_gemm(
    const _Float16* __restrict__ A, const _Float16* __restrict__ Bw,
    const float* __restrict__ qg, const float* __restrict__ kg,
    _Float16* __restrict__ Qg, _Float16* __restrict__ Kg, _Float16* __restrict__ Vtg)
{
    __shared__ __align__(16) char smem[34816];      // dbuf 32K | Ws 34.8K
    _Float16* Ws = (_Float16*)smem;                 // epilogue staging alias

    const int blk = blockIdx.x;
    const int xcd = blk & 7;
    const int t   = blk >> 3;                       // 0..191
    const int by  = xcd * 32 + (t & 31);
    const int bx  = t >> 5;                         // 0..5
    const int m0 = by * 128;
    const int n0 = bx * 128;

    const int tid = threadIdx.x;
    const int wv = tid >> 6, ln = tid & 63;
    const int lr = ln >> 2, lc = (ln & 3) * 8;
    const int wm = (wv >> 1) * 64, wn = (wv & 1) * 64;
    const int fr = ln & 15, fk = (ln >> 4) * 8;

    f32x4 acc[4][4] = {};
    const _Float16* ga = A  + (size_t)(m0 + wv * 16 + lr) * 256 + lc;
    const _Float16* gb = Bw + (size_t)(n0 + wv * 16 + lr) * 256 + lc;

    // prologue: stage k0=0 into buf0
    {
        _Float16* As0 = (_Float16*)smem;
        _Float16* Bs0 = As0 + 128 * 32;
        GLOAD_LDS16(ga,            As0 + (wv * 16) * 32);
        GLOAD_LDS16(ga + 64 * 256, As0 + (64 + wv * 16) * 32);
        GLOAD_LDS16(gb,            Bs0 + (wv * 16) * 32);
        GLOAD_LDS16(gb + 64 * 256, Bs0 + (64 + wv * 16) * 32);
    }
    __syncthreads();

#pragma unroll
    for (int ts = 0; ts < 8; ++ts) {
        const int b = ts & 1;
        _Float16* Asb = (_Float16*)(smem + b * 16384);
        _Float16* Bsb = Asb + 128 * 32;
        if (ts < 7) {                                // stage next tile first
            const int kn = (ts + 1) * 32;
            _Float16* Asn = (_Float16*)(smem + (b ^ 1) * 16384);
            _Float16* Bsn = Asn + 128 * 32;
            GLOAD_LDS16(ga + kn,            Asn + (wv * 16) * 32);
            GLOAD_LDS16(ga + kn + 64 * 256, Asn + (64 + wv * 16) * 32);
            GLOAD_LDS16(gb + kn,            Bsn + (wv * 16) * 32);
            GLOAD_LDS16(gb + kn + 64 * 256, Bsn + (64 + wv * 16) * 32);
        }
        f16x8 af[4], bf[4];
#pragma unroll
        for (int i = 0; i < 4; ++i)
            af[i] = *(const f16x8*)(Asb + (wm + i * 16 + fr) * 32 + fk);
#pragma unroll
        for (int j = 0; j < 4; ++j)
            bf[j] = *(const f16x8*)(Bsb + (wn + j * 16 + fr) * 32 + fk);
#pragma unroll
        for (int i = 0; i < 4; ++i)
#pragma unroll
            for (int j = 0; j < 4; ++j)
                acc[i][j] = __builtin_amdgcn_mfma_f32_16x16x32_f16(
                    af[i], bf[j], acc[i][j], 0, 0, 0);
        __syncthreads();   // drains vmcnt (staged loads) + fences buf reuse
    }

    const int cr = (ln >> 4) * 4, cc = ln & 15;
    const int kind = n0 >> 8;                 // 0=Q 1=K 2=V
    const int col0 = (n0 & 255) + wn;
    const int bb = m0 >> 12, l00 = m0 & 4095;
    const int hbase = (n0 & 255) >> 5;

    if (kind < 2) {
        // fused RMS-norm (q's D^-1/2 pre-scale cancels; scale-invariant)
        const float* gsrc = kind ? kg : qg;
        float gma[2][2];
#pragma unroll
        for (int jp = 0; jp < 2; ++jp)
#pragma unroll
            for (int jj = 0; jj < 2; ++jj)
                gma[jp][jj] = gsrc[((col0 >> 5) + jp) * 32 + jj * 16 + cc];
#pragma unroll
        for (int i = 0; i < 4; ++i)
#pragma unroll
            for (int r = 0; r < 4; ++r) {
                const int irow = wm + i * 16 + cr + r;
#pragma unroll
                for (int jp = 0; jp < 2; ++jp) {
                    const float a0 = acc[i][jp * 2][r];
                    const float a1 = acc[i][jp * 2 + 1][r];
                    float ss = a0 * a0 + a1 * a1;
                    ss += __shfl_xor(ss, 1);
                    ss += __shfl_xor(ss, 2);
                    ss += __shfl_xor(ss, 4);
                    ss += __shfl_xor(ss, 8);
                    const float sc = 5.656854249492381f / fmaxf(sqrtf(ss), 1e-12f);
                    Ws[irow * 136 + wn + jp * 32 + cc]      = (_Float16)(a0 * sc * gma[jp][0]);
                    Ws[irow * 136 + wn + jp * 32 + 16 + cc] = (_Float16)(a1 * sc * gma[jp][1]);
                }
            }
        __syncthreads();
        _Float16* P = kind ? Kg : Qg;
#pragma unroll
        for (int kk = 0; kk < 8; ++kk) {
            const int c = kk * 256 + tid;             // 0..2047 f16x8 chunks
            const int hh = c >> 9;
            const int rr = (c >> 2) & 127;
            const int part = (c & 3) * 8;
            f16x8 v8 = *(const f16x8*)(Ws + rr * 136 + hh * 32 + part);
            *(f16x8*)(P + ((size_t)(bb * 8 + hbase + hh) * 4096 + l00 + rr) * 32 + part) = v8;
        }
    } else {
        // V: transpose through LDS (stride 132: 2-way banks) -> [bh][e][4096]
#pragma unroll
        for (int i = 0; i < 4; ++i)
#pragma unroll
            for (int j = 0; j < 4; ++j) {
                const int colL = wn + j * 16 + cc;    // 0..127
                const int row0 = wm + i * 16 + cr;    // 4-aligned
                f16x4 v4 = { (_Float16)acc[i][j][0], (_Float16)acc[i][j][1],
                             (_Float16)acc[i][j][2], (_Float16)acc[i][j][3] };
                *(f16x4*)(Ws + colL * 132 + row0) = v4;
            }
        __syncthreads();
#pragma unroll
        for (int kk = 0; kk < 8; ++kk) {
            const int q = kk * 256 + tid;             // 0..2047
            const int c = q >> 4;                     // col 0..127
            const int seg = q & 15;                   // 8-row segment
            const int col = (n0 & 255) + c;
            const int hh = col >> 5, e = col & 31;
            f16x8 v8 = *(const f16x8*)(Ws + c * 132 + seg * 8);
            *(f16x8*)(Vtg + ((size_t)(bb * 8 + hh) * 32 + e) * 4096 + l00 + seg * 8) = v8;
        }
    }
}

// ---------------------------------------------------------------------------
// Per-chunk KV outer product via MFMA: one wave per chunk (verified r0 form).
// ---------------------------------------------------------------------------
__global__ __launch_bounds__(64) void k_chunk_kv(
    const _Float16* __restrict__ Kg, const _Float16* __restrict__ Vtg,
    float* __restrict__ kvbuf)
{
    __shared__ _Float16 Vp[32 * 136];   // [e][pos]
    __shared__ _Float16 Kp[32 * 136];   // [d][pos]
    const int blk = blockIdx.x;
    const int n  = blk & 31;
    const int bh = blk >> 5;
    const int h  = bh & 7;
    const float sl2 = exp2f(-(float)(h + 1)) * 1.44269504f;
    const int ln = threadIdx.x;
    const _Float16* Kc = Kg  + ((size_t)bh * 4096 + n * CHUNK_) * 32;
    const _Float16* Vc = Vtg + (size_t)bh * 32 * 4096 + n * CHUNK_;
#pragma unroll
    for (int i = 0; i < 8; ++i) {
        const int flat = i * 64 + ln;          // 0..511
        const int e = flat >> 4, seg = flat & 15;
        f16x8 v8 = *(const f16x8*)(Vc + (size_t)e * 4096 + seg * 8);
        *(f16x8*)(Vp + e * 136 + seg * 8) = v8;
        const int pos = flat >> 2, d0 = (flat & 3) * 8;
        f16x8 k8 = *(const f16x8*)(Kc + flat * 8);
#pragma unroll
        for (int j = 0; j < 8; ++j) Kp[(d0 + j) * 136 + pos] = k8[j];
    }
    __syncthreads();
    const int fr = ln & 15, fk = (ln >> 4) * 8;
    const float r = exp2f(sl2);
    float rj[8];
    rj[0] = 1.f;
#pragma unroll
    for (int j = 1; j < 8; ++j) rj[j] = rj[j - 1] * r;
    f32x4 acc[2][2] = {};
    for (int k0 = 0; k0 < 128; k0 += 32) {
        const float e0 = exp2f(-sl2 * (float)(CHUNK_ - (k0 + fk)));
        f16x8 av[2], bd[2];
#pragma unroll
        for (int i = 0; i < 2; ++i)
            av[i] = *(const f16x8*)(Vp + (i * 16 + fr) * 136 + k0 + fk);
#pragma unroll
        for (int jt = 0; jt < 2; ++jt) {
            f16x8 kraw = *(const f16x8*)(Kp + (jt * 16 + fr) * 136 + k0 + fk);
            f16x8 kb;
#pragma unroll
            for (int j = 0; j < 8; ++j)
                kb[j] = (_Float16)((float)kraw[j] * (e0 * rj[j]));
            bd[jt] = kb;
        }
#pragma unroll
        for (int i = 0; i < 2; ++i)
#pragma unroll
            for (int jt = 0; jt < 2; ++jt)
                acc[i][jt] = __builtin_amdgcn_mfma_f32_16x16x32_f16(
                    av[i], bd[jt], acc[i][jt], 0, 0, 0);
    }
    const int cr = (ln >> 4) * 4, cc = ln & 15;
    float* outp = kvbuf + (size_t)blk * 1024;
#pragma unroll
    for (int i = 0; i < 2; ++i)
#pragma unroll
        for (int jt = 0; jt < 2; ++jt)
#pragma unroll
            for (int rr = 0; rr < 4; ++rr)
                outp[(i * 16 + cr + rr) * 32 + jt * 16 + cc] = acc[i][jt][rr];
}

// ---------------------------------------------------------------------------
// Chunk-state scan: 256 single-wave blocks (verified r2 form).
// ---------------------------------------------------------------------------
__global__ __launch_bounds__(64) void k_scan(float* __restrict__ kvbuf)
{
    const int blk = blockIdx.x;            // 256 = 64 bh * 4 groups
    const int bh  = blk >> 2;
    const int grp = blk & 3;
    const int tid = threadIdx.x;           // 64
    const float slope = exp2f(-(float)((bh & 7) + 1));
    const float bd = __expf(-slope * (float)CHUNK_);
    float4 st = {0.f, 0.f, 0.f, 0.f};
    float4* base = (float4*)(kvbuf + (size_t)bh * NC_ * 1024) + grp * 64 + tid;
#pragma unroll
    for (int g = 0; g < 4; ++g) {
        float4 tmp[8];
#pragma unroll
        for (int k = 0; k < 8; ++k) tmp[k] = base[(g * 8 + k) * 256];
#pragma unroll
        for (int k = 0; k < 8; ++k) {
            base[(g * 8 + k) * 256] = st;
            st.x = bd * st.x + tmp[k].x;
            st.y = bd * st.y + tmp[k].y;
            st.z = bd * st.z + tmp[k].z;
            st.w = bd * st.w + tmp[k].w;
        }
    }
}

// ---------------------------------------------------------------------------
// MFMA attention, barrier-free + load-balanced triangle (verified r2 form).
// ---------------------------------------------------------------------------
__global__ __launch_bounds__(256) void k_attn(
    const _Float16* __restrict__ Qg, const _Float16* __restrict__ Kg,
    const _Float16* __restrict__ Vtg, const float* __restrict__ kvbuf,
    _Float16* __restrict__ attnp)
{
    __shared__ __align__(16) _Float16 Ss[128 * 144];   // S~ ; Os alias (own rows)
    const int blk = blockIdx.x;
    const int n  = blk & 31;
    const int bh = blk >> 5;
    const int h  = bh & 7;
    const float sl2 = exp2f(-(float)(h + 1)) * 1.44269504f;
    const int tid = threadIdx.x;
    const int wv = tid >> 6, ln = tid & 63;
    const int fr = ln & 15, fk = (ln >> 4) * 8;
    const int cr = (ln >> 4) * 4, cc = ln & 15;
    const int rb0 = wv;          // owned row-blocks (16 rows each)
    const int rb1 = 7 - wv;

    const _Float16* Qc = Qg + ((size_t)bh * 4096 + n * CHUNK_) * 32;
    const _Float16* Kc = Kg + ((size_t)bh * 4096 + n * CHUNK_) * 32;
    const _Float16* Vc = Vtg + (size_t)bh * 32 * 4096 + n * CHUNK_;
    const float* kvp = kvbuf + (size_t)blk * 1024;     // KV^T [e][d] f32

    f16x8 aq0 = *(const f16x8*)(Qc + (rb0 * 16 + fr) * 32 + fk);
    f16x8 aq1 = *(const f16x8*)(Qc + (rb1 * 16 + fr) * 32 + fk);

    f32x4 iacc[2][2] = {};
#pragma unroll
    for (int ct = 0; ct < 2; ++ct) {
        const float* kp = kvp + (ct * 16 + fr) * 32 + fk;
        f32x4 k0 = *(const f32x4*)kp;
        f32x4 k1 = *(const f32x4*)(kp + 4);
        f16x8 bkv = { (_Float16)k0[0], (_Float16)k0[1], (_Float16)k0[2], (_Float16)k0[3],
                      (_Float16)k1[0], (_Float16)k1[1], (_Float16)k1[2], (_Float16)k1[3] };
        iacc[0][ct] = __builtin_amdgcn_mfma_f32_16x16x32_f16(aq0, bkv, iacc[0][ct], 0, 0, 0);
        iacc[1][ct] = __builtin_amdgcn_mfma_f32_16x16x32_f16(aq1, bkv, iacc[1][ct], 0, 0, 0);
    }

    const float c1  = exp2f(-sl2);
    const float r16 = exp2f(sl2 * 16.f);
    float er0[4], er1[4];
    {
        float e0 = exp2f(-sl2 * (float)(rb0 * 16 + cr));
        float e1 = exp2f(-sl2 * (float)(rb1 * 16 + cr));
#pragma unroll
        for (int r = 0; r < 4; ++r) { er0[r] = e0; er1[r] = e1; e0 *= c1; e1 *= c1; }
    }

    float ej = exp2f(sl2 * (float)cc);
#pragma unroll
    for (int j = 0; j < 8; ++j) {
        if (j <= rb1) {                                // wave-uniform
            f16x8 bk = *(const f16x8*)(Kc + (j * 16 + fr) * 32 + fk);
            f32x4 z = {};
            f32x4 s1 = __builtin_amdgcn_mfma_f32_16x16x32_f16(aq1, bk, z, 0, 0, 0);
            f32x4 s0 = {};
            if (j <= rb0)
                s0 = __builtin_amdgcn_mfma_f32_16x16x32_f16(aq0, bk, z, 0, 0, 0);
            const int jcol = j * 16 + cc;
#pragma unroll
            for (int r = 0; r < 4; ++r) {
                const int i1 = rb1 * 16 + cr + r;
                const float w1 = (jcol <= i1) ? ej * er1[r] : 0.f;
                Ss[i1 * 144 + jcol] = (_Float16)(s1[r] * w1);
                if (j <= rb0) {
                    const int i0 = rb0 * 16 + cr + r;
                    const float w0 = (jcol <= i0) ? ej * er0[r] : 0.f;
                    Ss[i0 * 144 + jcol] = (_Float16)(s0[r] * w0);
                }
            }
        }
        ej *= r16;
    }

    {
        const int rbe = (wv & 1) ? rb1 : rb0;
#pragma unroll
        for (int r = 0; r < 4; ++r)
            Ss[(rbe * 16 + cr + r) * 144 + (rbe + 1) * 16 + cc] = (_Float16)0;
    }

    const int km0 = (rb0 >> 1) + 1;
    const int km1 = (rb1 >> 1) + 1;                    // km1 >= km0
    f32x4 oacc[2][2] = {};
#pragma unroll
    for (int k = 0; k < 4; ++k) {
        if (k < km1) {                                 // wave-uniform
            f16x8 bv0 = *(const f16x8*)(Vc + (size_t)(fr) * 4096 + k * 32 + fk);
            f16x8 bv1 = *(const f16x8*)(Vc + (size_t)(16 + fr) * 4096 + k * 32 + fk);
            f16x8 as1 = *(const f16x8*)(Ss + (rb1 * 16 + fr) * 144 + k * 32 + fk);
            oacc[1][0] = __builtin_amdgcn_mfma_f32_16x16x32_f16(as1, bv0, oacc[1][0], 0, 0, 0);
            oacc[1][1] = __builtin_amdgcn_mfma_f32_16x16x32_f16(as1, bv1, oacc[1][1], 0, 0, 0);
            if (k < km0) {
                f16x8 as0 = *(const f16x8*)(Ss + (rb0 * 16 + fr) * 144 + k * 32 + fk);
                oacc[0][0] = __builtin_amdgcn_mfma_f32_16x16x32_f16(as0, bv0, oacc[0][0], 0, 0, 0);
                oacc[0][1] = __builtin_amdgcn_mfma_f32_16x16x32_f16(as0, bv1, oacc[0][1], 0, 0, 0);
            }
        }
    }

#pragma unroll
    for (int r = 0; r < 4; ++r) {
        const int i0 = rb0 * 16 + cr + r;
        const int i1 = rb1 * 16 + cr + r;
        Ss[i0 * 144 + cc]      = (_Float16)(oacc[0][0][r] + er0[r] * iacc[0][0][r]);
        Ss[i0 * 144 + 16 + cc] = (_Float16)(oacc[0][1][r] + er0[r] * iacc[0][1][r]);
        Ss[i1 * 144 + cc]      = (_Float16)(oacc[1][0][r] + er1[r] * iacc[1][0][r]);
        Ss[i1 * 144 + 16 + cc] = (_Float16)(oacc[1][1][r] + er1[r] * iacc[1][1][r]);
    }
    _Float16* abase = attnp + ((size_t)bh * 4096 + n * CHUNK_) * 32;
    {
        const int rloc = ln >> 2, part = (ln & 3) * 8;
        const int i0 = rb0 * 16 + rloc;
        const int i1 = rb1 * 16 + rloc;
        f16x8 v0 = *(const f16x8*)(Ss + i0 * 144 + part);
        f16x8 v1 = *(const f16x8*)(Ss + i1 * 144 + part);
        *(f16x8*)(abase + i0 * 32 + part) = v0;
        *(f16x8*)(abase + i1 * 32 + part) = v1;
    }
}

// ---------------------------------------------------------------------------
// proj GEMM, 2-phase double-buffered (same schedule as qkv). B from prep'd
// f16 weights via global_load_lds. XCD-swizzled 1D grid (512 blocks).
// ---------------------------------------------------------------------------
__global__ __launch_bounds__(256) void k_proj_gemm(
    const _Float16* __restrict__ attnp, const _Float16* __restrict__ Bw,
    const float* __restrict__ bias, float* __restrict__ Cc)
{
    __shared__ __align__(16) char smem[32768];      // 2 x (As 8K + Bs 8K)
    const int blk = blockIdx.x;
    const int xcd = blk & 7;
    const int t   = blk >> 3;                       // 0..63
    const int m0 = (xcd * 32 + (t & 31)) * 128;
    const int n0 = (t >> 5) * 128;

    const int tid = threadIdx.x;
    const int wv = tid >> 6, ln = tid & 63;
    const int lr = ln >> 2;
    const int lc = (ln & 3) * 8;
    const int wm = (wv >> 1) * 64;
    const int wn = (wv & 1) * 64;
    const int fr = ln & 15;
    const int fk = (ln >> 4) * 8;

    f32x4 acc[4][4] = {};
    const int gmrow = m0 + wv * 16 + lr;
    const _Float16* ga = attnp +
        ((size_t)(gmrow >> 12) * 8 * 4096 + (gmrow & 4095)) * 32 + lc;
    const _Float16* gb = Bw + (size_t)(n0 + wv * 16 + lr) * 256 + lc;

    // prologue: stage k0=0 into buf0
    {
        _Float16* As0 = (_Float16*)smem;
        _Float16* Bs0 = As0 + 128 * 32;
        GLOAD_LDS16(ga,           As0 + (wv * 16) * 32);
        GLOAD_LDS16(ga + 64 * 32, As0 + (64 + wv * 16) * 32);
        GLOAD_LDS16(gb,           Bs0 + (wv * 16) * 32);
        GLOAD_LDS16(gb + 64 * 256, Bs0 + (64 + wv * 16) * 32);
    }
    __syncthreads();

#pragma unroll
    for (int ts = 0; ts < 8; ++ts) {
        const int b = ts & 1;
        _Float16* Asb = (_Float16*)(smem + b * 16384);
        _Float16* Bsb = Asb + 128 * 32;
        if (ts < 7) {
            const int kn = (ts + 1) * 32;
            const size_t hoff = (size_t)((ts + 1)) * (4096 * 32); // head stride in A
            _Float16* Asn = (_Float16*)(smem + (b ^ 1) * 16384);
            _Float16* Bsn = Asn + 128 * 32;
            GLOAD_LDS16(ga + hoff,           Asn + (wv * 16) * 32);
            GLOAD_LDS16(ga + hoff + 64 * 32, Asn + (64 + wv * 16) * 32);
            GLOAD_LDS16(gb + kn,             Bsn + (wv * 16) * 32);
            GLOAD_LDS16(gb + kn + 64 * 256,  Bsn + (64 + wv * 16) * 32);
        }
        f16x8 af[4], bf[4];
#pragma unroll
        for (int i = 0; i < 4; ++i)
            af[i] = *(const f16x8*)(Asb + (wm + i * 16 + fr) * 32 + fk);
#pragma unroll
        for (int j = 0; j < 4; ++j)
            bf[j] = *(const f16x8*)(Bsb + (wn + j * 16 + fr) * 32 + fk);
#pragma unroll
        for (int i = 0; i < 4; ++i)
#pragma unroll
            for (int j = 0; j < 4; ++j)
                acc[i][j] = __builtin_amdgcn_mfma_f32_16x16x32_f16(
                    af[i], bf[j], acc[i][j], 0, 0, 0);
        __syncthreads();
    }
    const int cr = (ln >> 4) * 4;
    const int cc = ln & 15;
#pragma unroll
    for (int i = 0; i < 4; ++i)
#pragma unroll
        for (int j = 0; j < 4; ++j) {
            const int row = m0 + wm + i * 16 + cr;
            const int col = n0 + wn + j * 16 + cc;
            float* cp = Cc + (size_t)row * 256 + col;
            const float bb = bias[col];
#pragma unroll
            for (int r = 0; r < 4; ++r) cp[(size_t)r * 256] = acc[i][j][r] + bb;
        }
}

// ---------------------------------------------------------------------------
extern "C" void kernel_launch(void* const* d_in, const int* in_sizes, int n_in,
                              void* d_out, int out_size, void* d_ws, size_t ws_size,
                              hipStream_t stream)
{
    const float* x     = (const float*)d_in[0];
    const float* rel   = (const float*)d_in[1];
    const float* qkv_w = (const float*)d_in[2];
    const float* qg    = (const float*)d_in[3];
    const float* kg    = (const float*)d_in[4];
    const float* pw    = (const float*)d_in[5];
    const float* pb    = (const float*)d_in[6];
    float* out = (float*)d_out;
    char* wsb = (char*)d_ws;

    float*    kvb   = (float*)wsb;                            // 8 MB
    _Float16* Qg    = (_Float16*)(wsb + ((size_t)8  << 20));  // 16 MB
    _Float16* Kg    = (_Float16*)(wsb + ((size_t)24 << 20));  // 16 MB
    _Float16* Vtg   = (_Float16*)(wsb + ((size_t)40 << 20));  // 16 MB
    _Float16* attnp = (_Float16*)(wsb + ((size_t)56 << 20));  // 16 MB
    _Float16* hb    = (_Float16*)(wsb + ((size_t)72 << 20));  // 16 MB
    _Float16* qwb   = (_Float16*)(wsb + ((size_t)88 << 20));  // 384 KB
    _Float16* pwb   = (_Float16*)(wsb + ((size_t)89 << 20));  // 128 KB

    k_prep<<<4352, 256, 0, stream>>>(x, rel, qkv_w, pw, hb, qwb, pwb);
    k_qkv_gemm<<<1536, 256, 0, stream>>>(hb, qwb, qg, kg, Qg, Kg, Vtg);
    k_chunk_kv<<<2048, 64, 0, stream>>>(Kg, Vtg, kvb);
    k_scan<<<256, 64, 0, stream>>>(kvb);
    k_attn<<<2048, 256, 0, stream>>>(Qg, Kg, Vtg, kvb, attnp);
    k_proj_gemm<<<512, 256, 0, stream>>>(attnp, pwb, pb, out);
}

// Round 7
// 168.906 us; speedup vs baseline: 1.0812x; 1.0178x over previous
//
#include <hip/hip_runtime.h>
#include <hip/hip_bf16.h>

#define B_ 8
#define L_ 4096
#define C_ 256
#define H_ 8
#define D_ 32
#define CHUNK_ 128
#define NC_ 32
#define M_ (B_*L_)   // 32768

typedef _Float16 f16x8 __attribute__((ext_vector_type(8)));
typedef _Float16 f16x4 __attribute__((ext_vector_type(4)));
typedef float    f32x4 __attribute__((ext_vector_type(4)));

#define GLOAD_LDS16(g, l) __builtin_amdgcn_global_load_lds( \
    (const __attribute__((address_space(1))) unsigned int*)(g), \
    (__attribute__((address_space(3))) unsigned int*)(l), 16, 0, 0)

// ---------------------------------------------------------------------------
// Prep: h = f16(x + rel_pos)  and  weights -> f16   (one launch)
// ---------------------------------------------------------------------------
__global__ __launch_bounds__(256) void k_prep(
    const float* __restrict__ x, const float* __restrict__ rel,
    const float* __restrict__ qw, const float* __restrict__ pw,
    _Float16* __restrict__ h, _Float16* __restrict__ qwb, _Float16* __restrict__ pwb)
{
    const int bx = blockIdx.x;
    if (bx < 4096) {
        const int i = (bx * 256 + threadIdx.x) * 8;
        float4 x0 = *(const float4*)(x + i);
        float4 x1 = *(const float4*)(x + i + 4);
        const int ri = i & (L_ * C_ - 1);
        float4 r0 = *(const float4*)(rel + ri);
        float4 r1 = *(const float4*)(rel + ri + 4);
        f16x8 o = { (_Float16)(x0.x + r0.x), (_Float16)(x0.y + r0.y),
                    (_Float16)(x0.z + r0.z), (_Float16)(x0.w + r0.w),
                    (_Float16)(x1.x + r1.x), (_Float16)(x1.y + r1.y),
                    (_Float16)(x1.z + r1.z), (_Float16)(x1.w + r1.w) };
        *(f16x8*)(h + i) = o;
    } else {
        const int i = ((bx - 4096) * 256 + threadIdx.x) * 4;
        const float* src; _Float16* dst; int off;
        if (i < 768 * 256) { src = qw; dst = qwb; off = i; }
        else               { src = pw; dst = pwb; off = i - 768 * 256; }
        float4 v = *(const float4*)(src + off);
        f16x4 o = { (_Float16)v.x, (_Float16)v.y, (_Float16)v.z, (_Float16)v.w };
        *(f16x4*)(dst + off) = o;
    }
}

// ---------------------------------------------------------------------------
// qkv GEMM, m97-style, XCD-swizzled 1D grid (1536 blocks):
// xcd = blk&7 owns 32 contiguous by-tiles x all 6 bx -> A-tile stays in one
// XCD's L2. Epilogue fuses RMS-norm (Q/K) -> packed Qg/Kg [bh][l][32];
// V -> LDS transpose (stride 132) -> Vtg [bh][e][4096].
// ---------------------------------------------------------------------------
__global__ __launch_bounds__(256) void k_qkv_gemm(
    const _Float16* __restrict__ A, const _Float16* __restrict__ Bw,
    const float* __restrict__ qg, const float* __restrict__ kg,
    _Float16* __restrict__ Qg, _Float16* __restrict__ Kg, _Float16* __restrict__ Vtg)
{
    __shared__ __align__(16) char smem[34816];      // max(As+Bs=16K, Ws)
    _Float16* As = (_Float16*)smem;                 // [128][32]
    _Float16* Bs = As + 128 * 32;                   // [128][32]
    _Float16* Ws = (_Float16*)smem;                 // epilogue staging

    const int blk = blockIdx.x;
    const int xcd = blk & 7;
    const int t   = blk >> 3;                       // 0..191
    const int by  = xcd * 32 + (t & 31);
    const int bx  = t >> 5;                         // 0..5
    const int m0 = by * 128;
    const int n0 = bx * 128;

    const int tid = threadIdx.x;
    const int wv = tid >> 6, ln = tid & 63;
    const int lr = ln >> 2, lc = (ln & 3) * 8;
    const int wm = (wv >> 1) * 64, wn = (wv & 1) * 64;
    const int fr = ln & 15, fk = (ln >> 4) * 8;

    f32x4 acc[4][4] = {};
    const _Float16* ga = A  + (size_t)(m0 + wv * 16 + lr) * 256 + lc;
    const _Float16* gb = Bw + (size_t)(n0 + wv * 16 + lr) * 256 + lc;

    for (int k0 = 0; k0 < 256; k0 += 32) {
        GLOAD_LDS16(ga + k0,            As + (wv * 16) * 32);
        GLOAD_LDS16(ga + k0 + 64 * 256, As + (64 + wv * 16) * 32);
        GLOAD_LDS16(gb + k0,            Bs + (wv * 16) * 32);
        GLOAD_LDS16(gb + k0 + 64 * 256, Bs + (64 + wv * 16) * 32);
        __syncthreads();
        f16x8 af[4], bf[4];
#pragma unroll
        for (int i = 0; i < 4; ++i)
            af[i] = *(const f16x8*)(As + (wm + i * 16 + fr) * 32 + fk);
#pragma unroll
        for (int j = 0; j < 4; ++j)
            bf[j] = *(const f16x8*)(Bs + (wn + j * 16 + fr) * 32 + fk);
#pragma unroll
        for (int i = 0; i < 4; ++i)
#pragma unroll
            for (int j = 0; j < 4; ++j)
                acc[i][j] = __builtin_amdgcn_mfma_f32_16x16x32_f16(
                    af[i], bf[j], acc[i][j], 0, 0, 0);
        __syncthreads();
    }

    const int cr = (ln >> 4) * 4, cc = ln & 15;
    const int kind = n0 >> 8;                 // 0=Q 1=K 2=V
    const int col0 = (n0 & 255) + wn;
    const int bb = m0 >> 12, l00 = m0 & 4095;
    const int hbase = (n0 & 255) >> 5;

    if (kind < 2) {
        // fused RMS-norm (q's D^-1/2 pre-scale cancels; scale-invariant)
        const float* gsrc = kind ? kg : qg;
        float gma[2][2];
#pragma unroll
        for (int jp = 0; jp < 2; ++jp)
#pragma unroll
            for (int jj = 0; jj < 2; ++jj)
                gma[jp][jj] = gsrc[((col0 >> 5) + jp) * 32 + jj * 16 + cc];
#pragma unroll
        for (int i = 0; i < 4; ++i)
#pragma unroll
            for (int r = 0; r < 4; ++r) {
                const int irow = wm + i * 16 + cr + r;
#pragma unroll
                for (int jp = 0; jp < 2; ++jp) {
                    const float a0 = acc[i][jp * 2][r];
                    const float a1 = acc[i][jp * 2 + 1][r];
                    float ss = a0 * a0 + a1 * a1;
                    ss += __shfl_xor(ss, 1);
                    ss += __shfl_xor(ss, 2);
                    ss += __shfl_xor(ss, 4);
                    ss += __shfl_xor(ss, 8);
                    const float sc = 5.656854249492381f / fmaxf(sqrtf(ss), 1e-12f);
                    Ws[irow * 136 + wn + jp * 32 + cc]      = (_Float16)(a0 * sc * gma[jp][0]);
                    Ws[irow * 136 + wn + jp * 32 + 16 + cc] = (_Float16)(a1 * sc * gma[jp][1]);
                }
            }
        __syncthreads();
        _Float16* P = kind ? Kg : Qg;
#pragma unroll
        for (int kk = 0; kk < 8; ++kk) {
            const int c = kk * 256 + tid;             // 0..2047 f16x8 chunks
            const int hh = c >> 9;
            const int rr = (c >> 2) & 127;
            const int part = (c & 3) * 8;
            f16x8 v8 = *(const f16x8*)(Ws + rr * 136 + hh * 32 + part);
            *(f16x8*)(P + ((size_t)(bb * 8 + hbase + hh) * 4096 + l00 + rr) * 32 + part) = v8;
        }
    } else {
        // V: transpose through LDS (stride 132: 2-way banks) -> [bh][e][4096]
#pragma unroll
        for (int i = 0; i < 4; ++i)
#pragma unroll
            for (int j = 0; j < 4; ++j) {
                const int colL = wn + j * 16 + cc;    // 0..127
                const int row0 = wm + i * 16 + cr;    // 4-aligned
                f16x4 v4 = { (_Float16)acc[i][j][0], (_Float16)acc[i][j][1],
                             (_Float16)acc[i][j][2], (_Float16)acc[i][j][3] };
                *(f16x4*)(Ws + colL * 132 + row0) = v4;
            }
        __syncthreads();
#pragma unroll
        for (int kk = 0; kk < 8; ++kk) {
            const int q = kk * 256 + tid;             // 0..2047
            const int c = q >> 4;                     // col 0..127
            const int seg = q & 15;                   // 8-row segment
            const int col = (n0 & 255) + c;
            const int hh = col >> 5, e = col & 31;
            f16x8 v8 = *(const f16x8*)(Ws + c * 132 + seg * 8);
            *(f16x8*)(Vtg + ((size_t)(bb * 8 + hh) * 32 + e) * 4096 + l00 + seg * 8) = v8;
        }
    }
}

// ---------------------------------------------------------------------------
// Per-chunk KV outer product via MFMA: one wave per chunk.
// KV^T[e][d] = sum_pos V[pos][e] * K[pos][d] * exp(-s*(128-pos)).
// A = V^T (Vtg rows), B = K^T (in-LDS scalar transpose), decay folded into
// the B fragment in-register. Output layout [e][d] (transposed vs before).
// ---------------------------------------------------------------------------
__global__ __launch_bounds__(64) void k_chunk_kv(
    const _Float16* __restrict__ Kg, const _Float16* __restrict__ Vtg,
    float* __restrict__ kvbuf)
{
    __shared__ _Float16 Vp[32 * 136];   // [e][pos]
    __shared__ _Float16 Kp[32 * 136];   // [d][pos]
    const int blk = blockIdx.x;
    const int n  = blk & 31;
    const int bh = blk >> 5;
    const int h  = bh & 7;
    const float sl2 = exp2f(-(float)(h + 1)) * 1.44269504f;
    const int ln = threadIdx.x;
    const _Float16* Kc = Kg  + ((size_t)bh * 4096 + n * CHUNK_) * 32;
    const _Float16* Vc = Vtg + (size_t)bh * 32 * 4096 + n * CHUNK_;
#pragma unroll
    for (int i = 0; i < 8; ++i) {
        const int flat = i * 64 + ln;          // 0..511
        const int e = flat >> 4, seg = flat & 15;
        f16x8 v8 = *(const f16x8*)(Vc + (size_t)e * 4096 + seg * 8);
        *(f16x8*)(Vp + e * 136 + seg * 8) = v8;
        const int pos = flat >> 2, d0 = (flat & 3) * 8;
        f16x8 k8 = *(const f16x8*)(Kc + flat * 8);
#pragma unroll
        for (int j = 0; j < 8; ++j) Kp[(d0 + j) * 136 + pos] = k8[j];
    }
    __syncthreads();
    const int fr = ln & 15, fk = (ln >> 4) * 8;
    const float r = exp2f(sl2);
    float rj[8];
    rj[0] = 1.f;
#pragma unroll
    for (int j = 1; j < 8; ++j) rj[j] = rj[j - 1] * r;
    f32x4 acc[2][2] = {};
    for (int k0 = 0; k0 < 128; k0 += 32) {
        const float e0 = exp2f(-sl2 * (float)(CHUNK_ - (k0 + fk)));
        f16x8 av[2], bd[2];
#pragma unroll
        for (int i = 0; i < 2; ++i)
            av[i] = *(const f16x8*)(Vp + (i * 16 + fr) * 136 + k0 + fk);
#pragma unroll
        for (int jt = 0; jt < 2; ++jt) {
            f16x8 kraw = *(const f16x8*)(Kp + (jt * 16 + fr) * 136 + k0 + fk);
            f16x8 kb;
#pragma unroll
            for (int j = 0; j < 8; ++j)
                kb[j] = (_Float16)((float)kraw[j] * (e0 * rj[j]));
            bd[jt] = kb;
        }
#pragma unroll
        for (int i = 0; i < 2; ++i)
#pragma unroll
            for (int jt = 0; jt < 2; ++jt)
                acc[i][jt] = __builtin_amdgcn_mfma_f32_16x16x32_f16(
                    av[i], bd[jt], acc[i][jt], 0, 0, 0);
    }
    const int cr = (ln >> 4) * 4, cc = ln & 15;
    float* outp = kvbuf + (size_t)blk * 1024;
#pragma unroll
    for (int i = 0; i < 2; ++i)
#pragma unroll
        for (int jt = 0; jt < 2; ++jt)
#pragma unroll
            for (int rr = 0; rr < 4; ++rr)
                outp[(i * 16 + cr + rr) * 32 + jt * 16 + cc] = acc[i][jt][rr];
}

// ---------------------------------------------------------------------------
// Chunk-state scan, batched prefetch (layout-agnostic: flat 1024 per chunk).
// ---------------------------------------------------------------------------
__global__ __launch_bounds__(256) void k_scan(float* __restrict__ kvbuf)
{
    const int bh = blockIdx.x;
    const int tid = threadIdx.x;
    const float slope = exp2f(-(float)((bh & 7) + 1));
    const float bd = __expf(-slope * (float)CHUNK_);
    float4 st = {0.f, 0.f, 0.f, 0.f};
    float4* base = (float4*)(kvbuf + (size_t)bh * NC_ * 1024) + tid;
#pragma unroll
    for (int g = 0; g < 4; ++g) {
        float4 tmp[8];
#pragma unroll
        for (int k = 0; k < 8; ++k) tmp[k] = base[(g * 8 + k) * 256];
#pragma unroll
        for (int k = 0; k < 8; ++k) {
            base[(g * 8 + k) * 256] = st;
            st.x = bd * st.x + tmp[k].x;
            st.y = bd * st.y + tmp[k].y;
            st.z = bd * st.z + tmp[k].z;
            st.w = bd * st.w + tmp[k].w;
        }
    }
}

// ---------------------------------------------------------------------------
// MFMA attention, low-LDS: Q/K/V fragments direct from global; only S̃ (and
// the small KV state) round-trip LDS. Os staging aliases Ss (barrier-guarded).
// kvbuf is [e][d] (KV^T) -> straight vector copy into KVt.
// ---------------------------------------------------------------------------
__global__ __launch_bounds__(256) void k_attn(
    const _Float16* __restrict__ Qg, const _Float16* __restrict__ Kg,
    const _Float16* __restrict__ Vtg, const float* __restrict__ kvbuf,
    _Float16* __restrict__ attnp)
{
    __shared__ __align__(16) _Float16 Ss[128 * 136];  // also Os[128][40] alias
    __shared__ __align__(16) _Float16 KVt[32 * 40];
    __shared__ float ejs[CHUNK_];
    _Float16* Os = Ss;
    const int blk = blockIdx.x;
    const int n  = blk & 31;
    const int bh = blk >> 5;
    const int h  = bh & 7;
    const float sl2 = exp2f(-(float)(h + 1)) * 1.44269504f;
    const int tid = threadIdx.x;
    const int wv = tid >> 6, ln = tid & 63;
    const int fr = ln & 15, fk = (ln >> 4) * 8;
    const int cr = (ln >> 4) * 4, cc = ln & 15;

    const _Float16* Qc = Qg + ((size_t)bh * 4096 + n * CHUNK_) * 32;
    const _Float16* Kc = Kg + ((size_t)bh * 4096 + n * CHUNK_) * 32;
    const _Float16* Vc = Vtg + (size_t)bh * 32 * 4096 + n * CHUNK_;

    {
        // kvbuf [e][d]: tid*4 covers 1024; e = tid>>3, d0 = (tid&7)*4
        const float* kvp = kvbuf + (size_t)blk * 1024;
        f32x4 kv4f = *(const f32x4*)(kvp + tid * 4);
        f16x4 kv4 = { (_Float16)kv4f[0], (_Float16)kv4f[1],
                      (_Float16)kv4f[2], (_Float16)kv4f[3] };
        *(f16x4*)(KVt + (tid >> 3) * 40 + (tid & 7) * 4) = kv4;
    }
    if (tid < CHUNK_) ejs[tid] = exp2f(sl2 * (float)tid);
    __syncthreads();

    f16x8 aq[2];
#pragma unroll
    for (int i = 0; i < 2; ++i)
        aq[i] = *(const f16x8*)(Qc + (wv * 32 + i * 16 + fr) * 32 + fk);

    f32x4 sacc[2][8] = {};
#pragma unroll
    for (int j = 0; j < 8; ++j) {
        f16x8 bk = *(const f16x8*)(Kc + (j * 16 + fr) * 32 + fk);
#pragma unroll
        for (int i = 0; i < 2; ++i)
            sacc[i][j] = __builtin_amdgcn_mfma_f32_16x16x32_f16(aq[i], bk, sacc[i][j], 0, 0, 0);
    }
    f32x4 iacc[2][2] = {};
#pragma unroll
    for (int ct = 0; ct < 2; ++ct) {
        f16x8 bkv = *(const f16x8*)(KVt + (ct * 16 + fr) * 40 + fk);
#pragma unroll
        for (int i = 0; i < 2; ++i)
            iacc[i][ct] = __builtin_amdgcn_mfma_f32_16x16x32_f16(aq[i], bkv, iacc[i][ct], 0, 0, 0);
    }
    // decay mask: w = ejs[jcol] * exp2(-sl2*irow), factorized, <= 1
    float ejr[8];
#pragma unroll
    for (int j = 0; j < 8; ++j) ejr[j] = ejs[j * 16 + cc];
    const float c1 = exp2f(-sl2);
    float qd_save[2][4];
#pragma unroll
    for (int i = 0; i < 2; ++i) {
        float er = exp2f(-sl2 * (float)(wv * 32 + i * 16 + cr));
#pragma unroll
        for (int r = 0; r < 4; ++r) {
            const int irow = wv * 32 + i * 16 + cr + r;
            qd_save[i][r] = er;
#pragma unroll
            for (int j = 0; j < 8; ++j) {
                const int jcol = j * 16 + cc;
                const float w = (jcol <= irow) ? ejr[j] * er : 0.f;
                Ss[irow * 136 + jcol] = (_Float16)(sacc[i][j][r] * w);
            }
            er *= c1;
        }
    }
    __syncthreads();

    f32x4 oacc[2][2] = {};
#pragma unroll
    for (int k = 0; k < 4; ++k) {
        f16x8 as[2], bv[2];
#pragma unroll
        for (int i = 0; i < 2; ++i)
            as[i] = *(const f16x8*)(Ss + (wv * 32 + i * 16 + fr) * 136 + k * 32 + fk);
#pragma unroll
        for (int ct = 0; ct < 2; ++ct)
            bv[ct] = *(const f16x8*)(Vc + (size_t)(ct * 16 + fr) * 4096 + k * 32 + fk);
#pragma unroll
        for (int i = 0; i < 2; ++i)
#pragma unroll
            for (int ct = 0; ct < 2; ++ct)
                oacc[i][ct] = __builtin_amdgcn_mfma_f32_16x16x32_f16(as[i], bv[ct], oacc[i][ct], 0, 0, 0);
    }
    __syncthreads();   // all Ss reads complete before Os (alias) is written
#pragma unroll
    for (int i = 0; i < 2; ++i)
#pragma unroll
        for (int r = 0; r < 4; ++r) {
            const int irow = wv * 32 + i * 16 + cr + r;
            const float qd = qd_save[i][r];
            Os[irow * 40 + cc]      = (_Float16)(oacc[i][0][r] + qd * iacc[i][0][r]);
            Os[irow * 40 + 16 + cc] = (_Float16)(oacc[i][1][r] + qd * iacc[i][1][r]);
        }
    __syncthreads();
    _Float16* abase = attnp + ((size_t)bh * 4096 + n * CHUNK_) * 32;
#pragma unroll
    for (int kk = 0; kk < 2; ++kk) {
        const int c = kk * 256 + tid;
        const int rr = c >> 2;
        const int part = (c & 3) * 8;
        *(f16x8*)(abase + rr * 32 + part) = *(const f16x8*)(Os + rr * 40 + part);
    }
}

// ---------------------------------------------------------------------------
// proj GEMM: out = attn @ proj_w^T + b, A from packed [bh][l][32].
// XCD-swizzled 1D grid (512 blocks).
// ---------------------------------------------------------------------------
__global__ __launch_bounds__(256) void k_proj_gemm(
    const _Float16* __restrict__ attnp, const _Float16* __restrict__ Bw,
    const float* __restrict__ bias, float* __restrict__ Cc)
{
    __shared__ _Float16 As[128 * 32];
    __shared__ _Float16 Bs[128 * 32];
    const int blk = blockIdx.x;
    const int xcd = blk & 7;
    const int t   = blk >> 3;                       // 0..63
    const int m0 = (xcd * 32 + (t & 31)) * 128;
    const int n0 = (t >> 5) * 128;

    const int tid = threadIdx.x;
    const int wv = tid >> 6, ln = tid & 63;
    const int lr = ln >> 2;
    const int lc = (ln & 3) * 8;
    const int wm = (wv >> 1) * 64;
    const int wn = (wv & 1) * 64;
    const int fr = ln & 15;
    const int fk = (ln >> 4) * 8;

    f32x4 acc[4][4] = {};
    const int gmrow = m0 + wv * 16 + lr;
    const _Float16* ga = attnp +
        ((size_t)(gmrow >> 12) * 8 * 4096 + (gmrow & 4095)) * 32 + lc;
    const _Float16* gb = Bw + (size_t)(n0 + wv * 16 + lr) * 256 + lc;

    for (int k0 = 0; k0 < 256; k0 += 32) {
        const size_t hoff = (size_t)(k0 >> 5) * (4096 * 32);
        GLOAD_LDS16(ga + hoff,           As + (wv * 16) * 32);
        GLOAD_LDS16(ga + hoff + 64 * 32, As + (64 + wv * 16) * 32);
        GLOAD_LDS16(gb + k0,             Bs + (wv * 16) * 32);
        GLOAD_LDS16(gb + k0 + 64 * 256,  Bs + (64 + wv * 16) * 32);
        __syncthreads();
        f16x8 af[4], bf[4];
#pragma unroll
        for (int i = 0; i < 4; ++i)
            af[i] = *(const f16x8*)(As + (wm + i * 16 + fr) * 32 + fk);
#pragma unroll
        for (int j = 0; j < 4; ++j)
            bf[j] = *(const f16x8*)(Bs + (wn + j * 16 + fr) * 32 + fk);
#pragma unroll
        for (int i = 0; i < 4; ++i)
#pragma unroll
            for (int j = 0; j < 4; ++j)
                acc[i][j] = __builtin_amdgcn_mfma_f32_16x16x32_f16(
                    af[i], bf[j], acc[i][j], 0, 0, 0);
        __syncthreads();
    }
    const int cr = (ln >> 4) * 4;
    const int cc = ln & 15;
#pragma unroll
    for (int i = 0; i < 4; ++i)
#pragma unroll
        for (int j = 0; j < 4; ++j) {
            const int row = m0 + wm + i * 16 + cr;
            const int col = n0 + wn + j * 16 + cc;
            float* cp = Cc + (size_t)row * 256 + col;
            const float bb = bias[col];
#pragma unroll
            for (int r = 0; r < 4; ++r) cp[(size_t)r * 256] = acc[i][j][r] + bb;
        }
}

// ---------------------------------------------------------------------------
extern "C" void kernel_launch(void* const* d_in, const int* in_sizes, int n_in,
                              void* d_out, int out_size, void* d_ws, size_t ws_size,
                              hipStream_t stream)
{
    const float* x     = (const float*)d_in[0];
    const float* rel   = (const float*)d_in[1];
    const float* qkv_w = (const float*)d_in[2];
    const float* qg    = (const float*)d_in[3];
    const float* kg    = (const float*)d_in[4];
    const float* pw    = (const float*)d_in[5];
    const float* pb    = (const float*)d_in[6];
    float* out = (float*)d_out;
    char* wsb = (char*)d_ws;

    float*    kvb   = (float*)wsb;                            // 8 MB
    _Float16* Qg    = (_Float16*)(wsb + ((size_t)8  << 20));  // 16 MB
    _Float16* Kg    = (_Float16*)(wsb + ((size_t)24 << 20));  // 16 MB
    _Float16* Vtg   = (_Float16*)(wsb + ((size_t)40 << 20));  // 16 MB
    _Float16* attnp = (_Float16*)(wsb + ((size_t)56 << 20));  // 16 MB
    _Float16* hb    = (_Float16*)(wsb + ((size_t)72 << 20));  // 16 MB
    _Float16* qwb   = (_Float16*)(wsb + ((size_t)88 << 20));  // 384 KB
    _Float16* pwb   = (_Float16*)(wsb + ((size_t)89 << 20));  // 128 KB

    k_prep<<<4352, 256, 0, stream>>>(x, rel, qkv_w, pw, hb, qwb, pwb);
    k_qkv_gemm<<<1536, 256, 0, stream>>>(hb, qwb, qg, kg, Qg, Kg, Vtg);
    k_chunk_kv<<<2048, 64, 0, stream>>>(Kg, Vtg, kvb);
    k_scan<<<64, 256, 0, stream>>>(kvb);
    k_attn<<<2048, 256, 0, stream>>>(Qg, Kg, Vtg, kvb, attnp);
    k_proj_gemm<<<512, 256, 0, stream>>>(attnp, pwb, pb, out);
}